// Round 8
// baseline (724.851 us; speedup 1.0000x reference)
//
#include <hip/hip_runtime.h>
#include <hip/hip_bf16.h>
#include <math.h>

#define B_  4
#define C_  64
#define H_  128
#define W_  128
#define L_  4096
#define E2  1024
// extended pixel grid 66x66 (zero border = zero-pad semantics), padded to 35 tiles
#define GE  66
#define GR  4356        // 66*66 valid rows
#define GP  4480        // padded to 35*128
#define GT  35          // G tile grid
#define WW  132         // assemble LDS window edge

typedef _Float16 f16;
typedef f16 f16x8 __attribute__((ext_vector_type(8)));
typedef float f32x4 __attribute__((ext_vector_type(4)));

__device__ __forceinline__ void gload16(const void* g, void* l) {
    __builtin_amdgcn_global_load_lds(
        (const __attribute__((address_space(1))) unsigned int*)g,
        (__attribute__((address_space(3))) unsigned int*)l, 16, 0, 0);
}

// ---------------- fused bilinear resize (128->64 align_corners) + transpose to
// Fext[b][r][c] f16 (r = (y+1)*66 + x+1; borders/tail pre-zeroed) + n2[r] = ||f_r||^2 ----------------
__global__ __launch_bounds__(256) void fbuild_kernel(const float* __restrict__ fg,
                                                     f16* __restrict__ Fext,
                                                     float* __restrict__ n2) {
    int y = blockIdx.x, b = blockIdx.y;
    int tid = threadIdx.x;
    __shared__ float T[64][65];
    const float sc = 127.0f / 63.0f;
    float yf = y * sc;
    int y0 = (int)floorf(yf); if (y0 > 127) y0 = 127;
    int y1 = min(y0 + 1, 127);
    float wy = yf - (float)y0;
    {
        int x = tid & 63;
        float xf = x * sc;
        int x0 = (int)floorf(xf); if (x0 > 127) x0 = 127;
        int x1 = min(x0 + 1, 127);
        float wx = xf - (float)x0;
        for (int cp = 0; cp < 16; ++cp) {
            int c = cp * 4 + (tid >> 6);
            const float* p = fg + (size_t)(b * 64 + c) * (128 * 128);
            float a = p[y0 * 128 + x0], bb = p[y0 * 128 + x1];
            float cc = p[y1 * 128 + x0], dd = p[y1 * 128 + x1];
            float t0 = a * (1.f - wy) + cc * wy;
            float t1 = bb * (1.f - wy) + dd * wy;
            T[c][x] = t0 * (1.f - wx) + t1 * wx;
        }
    }
    __syncthreads();
    int c = tid & 63, xi = tid >> 6;
    for (int j = 0; j < 16; ++j) {
        int x = xi + 4 * j;
        float v = T[c][x];
        int r = (y + 1) * GE + 1 + x;
        Fext[((size_t)b * GP + r) * 64 + c] = (f16)v;
        float s = v * v;
        #pragma unroll
        for (int off = 32; off; off >>= 1) s += __shfl_xor(s, off);
        if (c == 0) n2[b * GP + r] = s;
    }
}

// ---------------- nrm[p] = clamp(sqrt(3x3 boxsum of n2), 1e-4) ----------------
__global__ __launch_bounds__(128) void norm_kernel(const float* __restrict__ n2,
                                                   float* __restrict__ nrm_all) {
    int t = threadIdx.x, pb = blockIdx.x, b = blockIdx.y;
    int p = pb * 128 + t;
    int pe = ((p >> 6) + 1) * GE + (p & 63) + 1;
    const float* n2b = n2 + (size_t)b * GP;
    float s = 0.f;
    #pragma unroll
    for (int dy = -1; dy <= 1; ++dy)
        #pragma unroll
        for (int dx = -1; dx <= 1; ++dx) s += n2b[pe + dy * GE + dx];
    nrm_all[b * L_ + p] = fmaxf(sqrtf(s), 1e-4f);
}

// ---------------- VT[b][e][l] f16 : transposed 4x4xC background patches, batched ----------------
__global__ __launch_bounds__(256) void v_kernel(const float* __restrict__ bg,
                                                f16* __restrict__ VT_all) {
    int idx = blockIdx.x * 256 + threadIdx.x;
    int b = blockIdx.y;
    int l = idx & 4095, e = idx >> 12;
    int c = e >> 4, r = e & 15;
    int ky = r >> 2, kx = r & 3;
    int ly = l >> 6, lx = l & 63;
    int by = 2 * ly - 1 + ky, bx = 2 * lx - 1 + kx;
    float v = 0.f;
    if ((unsigned)by < 128u && (unsigned)bx < 128u)
        v = bg[((size_t)b * C_ + c) * (H_ * W_) + by * W_ + bx];
    VT_all[(size_t)b * E2 * L_ + idx] = (f16)v;
}

// ---------------- pixel Gram GEMM: G[r,c] = <F_r, F_c>, f16 out ----------------
// 128x128 tile, 4 waves, 16x16x32 f16 MFMA, K=64 (two BK-32 panels, m97 staging).
__global__ __launch_bounds__(256) void g_gemm(const f16* __restrict__ F,
                                              f16* __restrict__ G) {
    __shared__ __align__(16) f16 As0[128 * 32];
    __shared__ __align__(16) f16 As1[128 * 32];
    __shared__ __align__(16) f16 Bs0[128 * 32];
    __shared__ __align__(16) f16 Bs1[128 * 32];
    const int bx = blockIdx.x, by = blockIdx.y;
    const int tid = threadIdx.x;
    const int w = tid >> 6, lane = tid & 63;
    const int row0 = by * 128, col0 = bx * 128;

    const int srow = w * 32 + (lane >> 2);
    const int scol = (lane & 3) * 8;
    const f16* gA = F + (size_t)(row0 + srow) * 64 + scol;
    const f16* gB = F + (size_t)(col0 + srow) * 64 + scol;
    const int l0 = (w * 32) * 32, l1 = (w * 32 + 16) * 32;

    gload16(gA,                As0 + l0);
    gload16(gA + 16 * 64,      As0 + l1);
    gload16(gA + 32,           As1 + l0);
    gload16(gA + 32 + 16 * 64, As1 + l1);
    gload16(gB,                Bs0 + l0);
    gload16(gB + 16 * 64,      Bs0 + l1);
    gload16(gB + 32,           Bs1 + l0);
    gload16(gB + 32 + 16 * 64, Bs1 + l1);

    const int wm = w >> 1, wn = w & 1;
    const int mfm = lane & 15, quad = lane >> 4;
    f32x4 acc[4][4] = {};
    __syncthreads();
    {
        f16x8 af[4], bf[4];
        #pragma unroll
        for (int mi = 0; mi < 4; ++mi)
            af[mi] = *(const f16x8*)&As0[(wm * 64 + mi * 16 + mfm) * 32 + quad * 8];
        #pragma unroll
        for (int ni = 0; ni < 4; ++ni)
            bf[ni] = *(const f16x8*)&Bs0[(wn * 64 + ni * 16 + mfm) * 32 + quad * 8];
        #pragma unroll
        for (int mi = 0; mi < 4; ++mi)
            #pragma unroll
            for (int ni = 0; ni < 4; ++ni)
                acc[mi][ni] = __builtin_amdgcn_mfma_f32_16x16x32_f16(
                    af[mi], bf[ni], acc[mi][ni], 0, 0, 0);
    }
    {
        f16x8 af[4], bf[4];
        #pragma unroll
        for (int mi = 0; mi < 4; ++mi)
            af[mi] = *(const f16x8*)&As1[(wm * 64 + mi * 16 + mfm) * 32 + quad * 8];
        #pragma unroll
        for (int ni = 0; ni < 4; ++ni)
            bf[ni] = *(const f16x8*)&Bs1[(wn * 64 + ni * 16 + mfm) * 32 + quad * 8];
        #pragma unroll
        for (int mi = 0; mi < 4; ++mi)
            #pragma unroll
            for (int ni = 0; ni < 4; ++ni)
                acc[mi][ni] = __builtin_amdgcn_mfma_f32_16x16x32_f16(
                    af[mi], bf[ni], acc[mi][ni], 0, 0, 0);
    }

    const int orow = row0 + wm * 64;
    const int ocol = col0 + wn * 64;
    #pragma unroll
    for (int mi = 0; mi < 4; ++mi)
        #pragma unroll
        for (int r = 0; r < 4; ++r) {
            int row = orow + mi * 16 + quad * 4 + r;
            #pragma unroll
            for (int ni = 0; ni < 4; ++ni)
                G[(size_t)row * GP + ocol + ni * 16 + mfm] = (f16)acc[mi][ni][r];
        }
}

// ---------------- S assembly v2 (LDS-staged): S[p,l] = sum_{o in 3x3 diag} G[pe+o, le+o].
// For fixed dy, all 3 dx terms of tile (pblk,lblk) live in the 132x132 window
// W = G[r0+dy*66-1 .., c0+dy*66-1 ..]. 3 sequential dy stages; S partials in
// registers (32 p x 2 l per thread). Then exact tile-max -> flag; nz tiles
// store E=exp(logit) f16 + rowsum atomics. ----------------
__global__ __launch_bounds__(256) void assemble_kernel(const f16* __restrict__ G,
                                                       const float* __restrict__ nrm_b,
                                                       f16* __restrict__ Eb,
                                                       float* __restrict__ rowsum_b,
                                                       int* __restrict__ flags) {
    const int lblk = blockIdx.x, pblk = blockIdx.y;
    const int tid = threadIdx.x;
    const int wv = tid >> 6, lane = tid & 63;
    __shared__ f16 Wd[WW * WW];
    __shared__ float sred[4];

    const int r0 = (2 * pblk + 1) * GE + 1;
    const int c0 = (2 * lblk + 1) * GE + 1;

    float acc0[32] = {}, acc1[32] = {};

    #pragma unroll
    for (int dy = -1; dy <= 1; ++dy) {
        const int rbase = r0 + dy * GE - 1;
        const int cbase = c0 + dy * GE - 1;
        // load 132x132 window (rows/cols stay inside [0, GR) x [0, GP) for all blocks)
        const f16* Gw = G + (size_t)rbase * GP + cbase;
        for (int idx = tid; idx < WW * WW; idx += 256) {
            int rr = idx / WW, cc = idx - rr * WW;
            Wd[idx] = Gw[(size_t)rr * GP + cc];
        }
        __syncthreads();
        #pragma unroll
        for (int k = 0; k < 32; ++k) {
            const int pi = wv + 4 * k;
            const int rrb = pi + 1 + ((k >= 16) ? 2 : 0);   // +2*(pi>>6)
            float s0 = 0.f, s1 = 0.f;
            #pragma unroll
            for (int dx = -1; dx <= 1; ++dx) {
                const f16* row = Wd + (rrb + dx) * WW;
                s0 += (float)row[lane + dx + 1];
                s1 += (float)row[lane + dx + 67];
            }
            acc0[k] += s0; acc1[k] += s1;
        }
        __syncthreads();
    }

    // logits + exact tile max
    const float inl0 = 10.0f / nrm_b[lblk * 128 + lane];
    const float inl1 = 10.0f / nrm_b[lblk * 128 + 64 + lane];
    float mx = -1e30f;
    #pragma unroll
    for (int k = 0; k < 32; ++k) {
        float rp = 10.0f * nrm_b[pblk * 128 + wv + 4 * k];
        float lg0 = acc0[k] * inl0 - rp;
        float lg1 = acc1[k] * inl1 - rp;
        acc0[k] = lg0; acc1[k] = lg1;
        mx = fmaxf(mx, fmaxf(lg0, lg1));
    }
    #pragma unroll
    for (int off = 32; off; off >>= 1) mx = fmaxf(mx, __shfl_xor(mx, off));
    if (lane == 0) sred[wv] = mx;
    __syncthreads();
    float bmax = fmaxf(fmaxf(sred[0], sred[1]), fmaxf(sred[2], sred[3]));
    // f16 subnormal floor: logits below -17.5 can never round to nonzero f16
    int nz = bmax > -17.5f;
    if (tid == 0) flags[pblk * 32 + lblk] = nz;
    if (!nz) return;

    #pragma unroll
    for (int k = 0; k < 32; ++k) {
        int p = pblk * 128 + wv + 4 * k;
        float e0 = __expf(acc0[k]);
        float e1 = __expf(acc1[k]);
        Eb[(size_t)p * L_ + lblk * 128 + lane]      = (f16)e0;
        Eb[(size_t)p * L_ + lblk * 128 + 64 + lane] = (f16)e1;
        float v = e0 + e1;
        #pragma unroll
        for (int off = 32; off; off >>= 1) v += __shfl_xor(v, off);
        if (lane == 0) atomicAdd(&rowsum_b[p], v);
    }
}

// ---------------- PV MFMA GEMM (no split-K): OPT[e,p] = sum_l VT[e,l]*E[p,l],
// 256 blocks, flag-skips zero E-chunks (block-uniform). ----------------
__global__ __launch_bounds__(256)
void pv_gemm(const f16* __restrict__ A, const f16* __restrict__ Bt,
             f16* __restrict__ outp, const int* __restrict__ flags) {
    __shared__ __align__(16) f16 As0[128 * 32];
    __shared__ __align__(16) f16 As1[128 * 32];
    __shared__ __align__(16) f16 Bs0[128 * 32];
    __shared__ __align__(16) f16 Bs1[128 * 32];
    const int lin = blockIdx.x;
    const int by = lin & 7;          // e block
    const int bx = lin >> 3;         // p block

    const int tid = threadIdx.x;
    const int w = tid >> 6, lane = tid & 63;
    const int row0 = by * 128, col0 = bx * 128;

    const int srow = w * 32 + (lane >> 2);
    const int scol = (lane & 3) * 8;
    const f16* gA = A + (size_t)(row0 + srow) * L_ + scol;
    const f16* gB = Bt + (size_t)(col0 + srow) * L_ + scol;
    const int l0 = (w * 32) * 32, l1 = (w * 32 + 16) * 32;

    const int wm = w >> 1, wn = w & 1;
    const int mfm = lane & 15, quad = lane >> 4;
    f32x4 acc[4][4] = {};

    for (int k0 = 0; k0 < L_; k0 += 64) {
        if (!flags[bx * 32 + (k0 >> 7)]) continue;
        gload16(gA + k0,                        As0 + l0);
        gload16(gA + k0 + (size_t)16 * L_,      As0 + l1);
        gload16(gA + k0 + 32,                   As1 + l0);
        gload16(gA + k0 + 32 + (size_t)16 * L_, As1 + l1);
        gload16(gB + k0,                        Bs0 + l0);
        gload16(gB + k0 + (size_t)16 * L_,      Bs0 + l1);
        gload16(gB + k0 + 32,                   Bs1 + l0);
        gload16(gB + k0 + 32 + (size_t)16 * L_, Bs1 + l1);
        __syncthreads();
        {
            f16x8 af[4], bf[4];
            #pragma unroll
            for (int mi = 0; mi < 4; ++mi)
                af[mi] = *(const f16x8*)&As0[(wm * 64 + mi * 16 + mfm) * 32 + quad * 8];
            #pragma unroll
            for (int ni = 0; ni < 4; ++ni)
                bf[ni] = *(const f16x8*)&Bs0[(wn * 64 + ni * 16 + mfm) * 32 + quad * 8];
            #pragma unroll
            for (int mi = 0; mi < 4; ++mi)
                #pragma unroll
                for (int ni = 0; ni < 4; ++ni)
                    acc[mi][ni] = __builtin_amdgcn_mfma_f32_16x16x32_f16(
                        af[mi], bf[ni], acc[mi][ni], 0, 0, 0);
        }
        {
            f16x8 af[4], bf[4];
            #pragma unroll
            for (int mi = 0; mi < 4; ++mi)
                af[mi] = *(const f16x8*)&As1[(wm * 64 + mi * 16 + mfm) * 32 + quad * 8];
            #pragma unroll
            for (int ni = 0; ni < 4; ++ni)
                bf[ni] = *(const f16x8*)&Bs1[(wn * 64 + ni * 16 + mfm) * 32 + quad * 8];
            #pragma unroll
            for (int mi = 0; mi < 4; ++mi)
                #pragma unroll
                for (int ni = 0; ni < 4; ++ni)
                    acc[mi][ni] = __builtin_amdgcn_mfma_f32_16x16x32_f16(
                        af[mi], bf[ni], acc[mi][ni], 0, 0, 0);
        }
        __syncthreads();
    }

    const int orow = row0 + wm * 64;
    const int ocol = col0 + wn * 64;
    #pragma unroll
    for (int mi = 0; mi < 4; ++mi) {
        #pragma unroll
        for (int r = 0; r < 4; ++r) {
            int row = orow + mi * 16 + quad * 4 + r;
            #pragma unroll
            for (int ni = 0; ni < 4; ++ni)
                outp[(size_t)row * L_ + ocol + ni * 16 + mfm] = (f16)acc[mi][ni][r];
        }
    }
}

// ---------------- conv_transpose overlap-add gather on OPT[e][p] layout ----------------
__global__ __launch_bounds__(256) void gather_kernel(const f16* __restrict__ OPT,
                                                     const float* __restrict__ rowsum,
                                                     float* __restrict__ out_b) {
    int idx = blockIdx.x * 256 + threadIdx.x;
    if (idx >= C_ * H_ * W_) return;
    int X = idx & 127, Y = (idx >> 7) & 127, c = idx >> 14;
    int kyp = (Y + 1) & 1;
    int kxp = (X + 1) & 1;
    float sum = 0.f;
    #pragma unroll
    for (int ky = kyp; ky < 4; ky += 2) {
        int py = (Y + 1 - ky) >> 1;
        if ((unsigned)py >= 64u) continue;
        #pragma unroll
        for (int kx = kxp; kx < 4; kx += 2) {
            int px = (X + 1 - kx) >> 1;
            if ((unsigned)px >= 64u) continue;
            int p = py * 64 + px;
            int e = c * 16 + ky * 4 + kx;
            sum += (float)OPT[(size_t)e * L_ + p] * __builtin_amdgcn_rcpf(rowsum[p]);
        }
    }
    out_b[idx] = 0.25f * sum;
}

extern "C" void kernel_launch(void* const* d_in, const int* in_sizes, int n_in,
                              void* d_out, int out_size, void* d_ws, size_t ws_size,
                              hipStream_t stream) {
    const float* bg = (const float*)d_in[0];
    const float* fg = (const float*)d_in[1];
    float* out = (float*)d_out;
    char* w8 = (char*)d_ws;

    // workspace (bytes), total ~118 MB (ws_size = 256 MiB per fill counters)
    f16*   Fext       = (f16*)  (w8);                 //  2,293,760  B x 4480 x 64
    float* n2         = (float*)(w8 + 2293760);       //     71,680  B x 4480
    float* nrm_all    = (float*)(w8 + 2365440);       //     65,536  B x 4096
    float* rowsum_all = (float*)(w8 + 2430976);       //     65,536  B x 4096
    int*   flags      = (int*)  (w8 + 2496512);       //      4,096  32 x 32
    f16*   VT_all     = (f16*)  (w8 + 2500608);       // 33,554,432  B x E2 x L
    f16*   G          = (f16*)  (w8 + 36055040);      // 40,140,800  4480 x 4480 (per-sample)
    f16*   Eb         = (f16*)  (w8 + 76195840);      // 33,554,432  (per-sample)
    f16*   OPT        = (f16*)  (w8 + 109750272);     //  8,388,608  E2 x L (per-sample)

    hipMemsetAsync(Fext, 0, (size_t)B_ * GP * 64 * sizeof(f16), stream);
    hipMemsetAsync(n2, 0, (size_t)B_ * GP * sizeof(float), stream);
    hipMemsetAsync(rowsum_all, 0, (size_t)B_ * L_ * sizeof(float), stream);

    fbuild_kernel<<<dim3(64, B_), 256, 0, stream>>>(fg, Fext, n2);
    norm_kernel<<<dim3(32, B_), 128, 0, stream>>>(n2, nrm_all);
    v_kernel<<<dim3((L_ * E2) / 256, B_), 256, 0, stream>>>(bg, VT_all);

    for (int b = 0; b < B_; ++b) {
        const f16* F_b     = Fext + (size_t)b * GP * 64;
        const float* nrm_b = nrm_all + (size_t)b * L_;
        float* rowsum_b    = rowsum_all + (size_t)b * L_;
        const f16* VT_b    = VT_all + (size_t)b * E2 * L_;
        float* out_b       = out + (size_t)b * C_ * H_ * W_;

        g_gemm<<<dim3(GT, GT), 256, 0, stream>>>(F_b, G);
        assemble_kernel<<<dim3(32, 32), 256, 0, stream>>>(
            G, nrm_b, Eb, rowsum_b, flags);
        pv_gemm<<<256, 256, 0, stream>>>(VT_b, Eb, OPT, flags);
        gather_kernel<<<(C_ * H_ * W_) / 256, 256, 0, stream>>>(OPT, rowsum_b, out_b);
    }
}

// Round 9
// 402.719 us; speedup vs baseline: 1.7999x; 1.7999x over previous
//
#include <hip/hip_runtime.h>
#include <hip/hip_bf16.h>
#include <math.h>

#define B_  4
#define C_  64
#define H_  128
#define W_  128
#define L_  4096
#define E2  1024
// extended pixel grid 66x66 (zero border = zero-pad semantics), padded
#define GE  66
#define GR  4356        // 66*66 valid rows
#define GP  4480        // padded row/col stride
#define HT  35          // H tile grid (stride-126 overlapping 128-tiles)
#define GSTR 130        // LDS G-tile stride (pad vs 128)

typedef _Float16 f16;
typedef f16 f16x2 __attribute__((ext_vector_type(2)));
typedef f16 f16x8 __attribute__((ext_vector_type(8)));
typedef float f32x4 __attribute__((ext_vector_type(4)));

__device__ __forceinline__ void gload16(const void* g, void* l) {
    __builtin_amdgcn_global_load_lds(
        (const __attribute__((address_space(1))) unsigned int*)g,
        (__attribute__((address_space(3))) unsigned int*)l, 16, 0, 0);
}

// ---------------- fused bilinear resize (128->64 align_corners) + transpose to
// Fext[b][r][c] f16 (r = (y+1)*66 + x+1; borders/tail pre-zeroed) + n2[r] ----------------
__global__ __launch_bounds__(256) void fbuild_kernel(const float* __restrict__ fg,
                                                     f16* __restrict__ Fext,
                                                     float* __restrict__ n2) {
    int y = blockIdx.x, b = blockIdx.y;
    int tid = threadIdx.x;
    __shared__ float T[64][65];
    const float sc = 127.0f / 63.0f;
    float yf = y * sc;
    int y0 = (int)floorf(yf); if (y0 > 127) y0 = 127;
    int y1 = min(y0 + 1, 127);
    float wy = yf - (float)y0;
    {
        int x = tid & 63;
        float xf = x * sc;
        int x0 = (int)floorf(xf); if (x0 > 127) x0 = 127;
        int x1 = min(x0 + 1, 127);
        float wx = xf - (float)x0;
        for (int cp = 0; cp < 16; ++cp) {
            int c = cp * 4 + (tid >> 6);
            const float* p = fg + (size_t)(b * 64 + c) * (128 * 128);
            float a = p[y0 * 128 + x0], bb = p[y0 * 128 + x1];
            float cc = p[y1 * 128 + x0], dd = p[y1 * 128 + x1];
            float t0 = a * (1.f - wy) + cc * wy;
            float t1 = bb * (1.f - wy) + dd * wy;
            T[c][x] = t0 * (1.f - wx) + t1 * wx;
        }
    }
    __syncthreads();
    int c = tid & 63, xi = tid >> 6;
    for (int j = 0; j < 16; ++j) {
        int x = xi + 4 * j;
        float v = T[c][x];
        int r = (y + 1) * GE + 1 + x;
        Fext[((size_t)b * GP + r) * 64 + c] = (f16)v;
        float s = v * v;
        #pragma unroll
        for (int off = 32; off; off >>= 1) s += __shfl_xor(s, off);
        if (c == 0) n2[b * GP + r] = s;
    }
}

// ---------------- nrm[p] = clamp(sqrt(3x3 boxsum of n2), 1e-4) ----------------
__global__ __launch_bounds__(128) void norm_kernel(const float* __restrict__ n2,
                                                   float* __restrict__ nrm_all) {
    int t = threadIdx.x, pb = blockIdx.x, b = blockIdx.y;
    int p = pb * 128 + t;
    int pe = ((p >> 6) + 1) * GE + (p & 63) + 1;
    const float* n2b = n2 + (size_t)b * GP;
    float s = 0.f;
    #pragma unroll
    for (int dy = -1; dy <= 1; ++dy)
        #pragma unroll
        for (int dx = -1; dx <= 1; ++dx) s += n2b[pe + dy * GE + dx];
    nrm_all[b * L_ + p] = fmaxf(sqrtf(s), 1e-4f);
}

// ---------------- VT[b][e][l] f16 : transposed 4x4xC background patches ----------------
__global__ __launch_bounds__(256) void v_kernel(const float* __restrict__ bg,
                                                f16* __restrict__ VT_all) {
    int idx = blockIdx.x * 256 + threadIdx.x;
    int b = blockIdx.y;
    int l = idx & 4095, e = idx >> 12;
    int c = e >> 4, r = e & 15;
    int ky = r >> 2, kx = r & 3;
    int ly = l >> 6, lx = l & 63;
    int by = 2 * ly - 1 + ky, bx = 2 * lx - 1 + kx;
    float v = 0.f;
    if ((unsigned)by < 128u && (unsigned)bx < 128u)
        v = bg[((size_t)b * C_ + c) * (H_ * W_) + by * W_ + bx];
    VT_all[(size_t)b * E2 * L_ + idx] = (f16)v;
}

// ---------------- pixel Gram GEMM + fused dx-diag-sum epilogue ----------------
// Overlapping 128x128 tiles at stride 126 (35x35 grid). MFMA computes the G
// tile (K=64, two BK-32 panels, m97 staging); epilogue stores it to LDS and
// emits H[r,c] = G[r-1,c-1]+G[r,c]+G[r+1,c+1] for interior rows/cols 1..126.
// H is stored column-shifted: Hs[r][cc] = H[r][cc+1] (keeps f16x2 writes and
// the assemble reads 4B-aligned). Interior regions are write-disjoint.
__global__ __launch_bounds__(256) void g_gemm(const f16* __restrict__ F,
                                              f16* __restrict__ Hs) {
    __shared__ __align__(16) f16 pool[128 * GSTR];   // 33280 B; staging aliases Gs
    f16* As0 = pool;
    f16* As1 = pool + 4096;
    f16* Bs0 = pool + 8192;
    f16* Bs1 = pool + 12288;
    f16* Gs  = pool;
    const int bx = blockIdx.x, by = blockIdx.y;
    const int tid = threadIdx.x;
    const int w = tid >> 6, lane = tid & 63;
    const int row0 = by * 126, col0 = bx * 126;

    const int srow = w * 32 + (lane >> 2);
    const int scol = (lane & 3) * 8;
    const f16* gA = F + (size_t)(row0 + srow) * 64 + scol;
    const f16* gB = F + (size_t)(col0 + srow) * 64 + scol;
    const int l0 = (w * 32) * 32, l1 = (w * 32 + 16) * 32;

    gload16(gA,                As0 + l0);
    gload16(gA + 16 * 64,      As0 + l1);
    gload16(gA + 32,           As1 + l0);
    gload16(gA + 32 + 16 * 64, As1 + l1);
    gload16(gB,                Bs0 + l0);
    gload16(gB + 16 * 64,      Bs0 + l1);
    gload16(gB + 32,           Bs1 + l0);
    gload16(gB + 32 + 16 * 64, Bs1 + l1);

    const int wm = w >> 1, wn = w & 1;
    const int mfm = lane & 15, quad = lane >> 4;
    f32x4 acc[4][4] = {};
    __syncthreads();
    {
        f16x8 af[4], bf[4];
        #pragma unroll
        for (int mi = 0; mi < 4; ++mi)
            af[mi] = *(const f16x8*)&As0[(wm * 64 + mi * 16 + mfm) * 32 + quad * 8];
        #pragma unroll
        for (int ni = 0; ni < 4; ++ni)
            bf[ni] = *(const f16x8*)&Bs0[(wn * 64 + ni * 16 + mfm) * 32 + quad * 8];
        #pragma unroll
        for (int mi = 0; mi < 4; ++mi)
            #pragma unroll
            for (int ni = 0; ni < 4; ++ni)
                acc[mi][ni] = __builtin_amdgcn_mfma_f32_16x16x32_f16(
                    af[mi], bf[ni], acc[mi][ni], 0, 0, 0);
    }
    {
        f16x8 af[4], bf[4];
        #pragma unroll
        for (int mi = 0; mi < 4; ++mi)
            af[mi] = *(const f16x8*)&As1[(wm * 64 + mi * 16 + mfm) * 32 + quad * 8];
        #pragma unroll
        for (int ni = 0; ni < 4; ++ni)
            bf[ni] = *(const f16x8*)&Bs1[(wn * 64 + ni * 16 + mfm) * 32 + quad * 8];
        #pragma unroll
        for (int mi = 0; mi < 4; ++mi)
            #pragma unroll
            for (int ni = 0; ni < 4; ++ni)
                acc[mi][ni] = __builtin_amdgcn_mfma_f32_16x16x32_f16(
                    af[mi], bf[ni], acc[mi][ni], 0, 0, 0);
    }
    __syncthreads();   // staging LDS dead; safe to overwrite with Gs
    #pragma unroll
    for (int mi = 0; mi < 4; ++mi)
        #pragma unroll
        for (int r = 0; r < 4; ++r) {
            int rl = wm * 64 + mi * 16 + quad * 4 + r;
            #pragma unroll
            for (int ni = 0; ni < 4; ++ni)
                Gs[rl * GSTR + wn * 64 + ni * 16 + mfm] = (f16)acc[mi][ni][r];
        }
    __syncthreads();
    if (lane < 63) {
        int c1 = 2 * lane + 1;
        for (int j = 0; j < 32; ++j) {
            int r = 1 + w + 4 * j;
            if (r > 126) break;
            float h1 = (float)Gs[(r - 1) * GSTR + c1 - 1] + (float)Gs[r * GSTR + c1]
                     + (float)Gs[(r + 1) * GSTR + c1 + 1];
            float h2 = (float)Gs[(r - 1) * GSTR + c1] + (float)Gs[r * GSTR + c1 + 1]
                     + (float)Gs[(r + 1) * GSTR + c1 + 2];
            f16x2 hv; hv.x = (f16)h1; hv.y = (f16)h2;
            *(f16x2*)&Hs[(size_t)(row0 + r) * GP + col0 + 2 * lane] = hv;
        }
    }
}

// ---------------- S assembly v3: S[p,l] = sum_dy H[pe+dy*66, le+dy*66].
// 3 coalesced f16x2 global reads per output pair; exp'd tile buffered in LDS
// (keeps VGPR low — round-8 lesson); exact tile max -> flag; nz tiles copy
// LDS -> Eb + rowsum atomics. ----------------
__global__ __launch_bounds__(256) void assemble_kernel(const f16* __restrict__ Hs,
                                                       const float* __restrict__ nrm_b,
                                                       f16* __restrict__ Eb,
                                                       float* __restrict__ rowsum_b,
                                                       int* __restrict__ flags) {
    const int lblk = blockIdx.x, pblk = blockIdx.y;
    const int tid = threadIdx.x, wv = tid >> 6, lane = tid & 63;
    __shared__ f16 Ss[128 * 128];
    __shared__ float nlv[128], npv[128], sred[4];
    if (tid < 128) nlv[tid] = 10.0f / nrm_b[lblk * 128 + tid];
    else           npv[tid - 128] = 10.0f * nrm_b[pblk * 128 + tid - 128];
    __syncthreads();

    const int ly_loc = lane >> 5;
    const int lx = 2 * (lane & 31);
    const int l_local = ly_loc * 64 + lx;
    const int gly = lblk * 2 + ly_loc;
    const float inl0 = nlv[l_local], inl1 = nlv[l_local + 1];

    float mx = -1e30f;
    for (int k = 0; k < 32; ++k) {
        int ip = wv + 4 * k;
        int p = pblk * 128 + ip;
        int pe = 66 * ((p >> 6) + 1) + (p & 63) + 1;
        float s0 = 0.f, s1 = 0.f;
        #pragma unroll
        for (int dy = -1; dy <= 1; ++dy) {
            f16x2 v = *(const f16x2*)&Hs[(size_t)(pe + dy * 66) * GP + 66 * (gly + 1 + dy) + lx];
            s0 += (float)v.x; s1 += (float)v.y;
        }
        float rp = npv[ip];
        float lg0 = s0 * inl0 - rp;
        float lg1 = s1 * inl1 - rp;
        mx = fmaxf(mx, fmaxf(lg0, lg1));
        f16x2 ev; ev.x = (f16)__expf(lg0); ev.y = (f16)__expf(lg1);
        *(f16x2*)&Ss[ip * 128 + l_local] = ev;
    }
    #pragma unroll
    for (int off = 32; off; off >>= 1) mx = fmaxf(mx, __shfl_xor(mx, off));
    if (lane == 0) sred[wv] = mx;
    __syncthreads();
    float bmax = fmaxf(fmaxf(sred[0], sred[1]), fmaxf(sred[2], sred[3]));
    // f16 subnormal floor: logits below -17.5 can never round to nonzero f16
    int nz = bmax > -17.5f;
    if (tid == 0) flags[pblk * 32 + lblk] = nz;
    if (!nz) return;

    for (int k = 0; k < 32; ++k) {
        int ip = wv + 4 * k;
        int p = pblk * 128 + ip;
        f16x2 ev = *(const f16x2*)&Ss[ip * 128 + l_local];
        *(f16x2*)&Eb[(size_t)p * L_ + lblk * 128 + l_local] = ev;
        float v = (float)ev.x + (float)ev.y;
        #pragma unroll
        for (int off = 32; off; off >>= 1) v += __shfl_xor(v, off);
        if (lane == 0) atomicAdd(&rowsum_b[p], v);
    }
}

// ---------------- PV MFMA GEMM (no split-K): OPT[e,p] = sum_l VT[e,l]*E[p,l],
// 256 blocks, flag-skips zero E-chunks (block-uniform). ----------------
__global__ __launch_bounds__(256)
void pv_gemm(const f16* __restrict__ A, const f16* __restrict__ Bt,
             f16* __restrict__ outp, const int* __restrict__ flags) {
    __shared__ __align__(16) f16 As0[128 * 32];
    __shared__ __align__(16) f16 As1[128 * 32];
    __shared__ __align__(16) f16 Bs0[128 * 32];
    __shared__ __align__(16) f16 Bs1[128 * 32];
    const int lin = blockIdx.x;
    const int by = lin & 7;          // e block
    const int bx = lin >> 3;         // p block

    const int tid = threadIdx.x;
    const int w = tid >> 6, lane = tid & 63;
    const int row0 = by * 128, col0 = bx * 128;

    const int srow = w * 32 + (lane >> 2);
    const int scol = (lane & 3) * 8;
    const f16* gA = A + (size_t)(row0 + srow) * L_ + scol;
    const f16* gB = Bt + (size_t)(col0 + srow) * L_ + scol;
    const int l0 = (w * 32) * 32, l1 = (w * 32 + 16) * 32;

    const int wm = w >> 1, wn = w & 1;
    const int mfm = lane & 15, quad = lane >> 4;
    f32x4 acc[4][4] = {};

    for (int k0 = 0; k0 < L_; k0 += 64) {
        if (!flags[bx * 32 + (k0 >> 7)]) continue;
        gload16(gA + k0,                        As0 + l0);
        gload16(gA + k0 + (size_t)16 * L_,      As0 + l1);
        gload16(gA + k0 + 32,                   As1 + l0);
        gload16(gA + k0 + 32 + (size_t)16 * L_, As1 + l1);
        gload16(gB + k0,                        Bs0 + l0);
        gload16(gB + k0 + (size_t)16 * L_,      Bs0 + l1);
        gload16(gB + k0 + 32,                   Bs1 + l0);
        gload16(gB + k0 + 32 + (size_t)16 * L_, Bs1 + l1);
        __syncthreads();
        {
            f16x8 af[4], bf[4];
            #pragma unroll
            for (int mi = 0; mi < 4; ++mi)
                af[mi] = *(const f16x8*)&As0[(wm * 64 + mi * 16 + mfm) * 32 + quad * 8];
            #pragma unroll
            for (int ni = 0; ni < 4; ++ni)
                bf[ni] = *(const f16x8*)&Bs0[(wn * 64 + ni * 16 + mfm) * 32 + quad * 8];
            #pragma unroll
            for (int mi = 0; mi < 4; ++mi)
                #pragma unroll
                for (int ni = 0; ni < 4; ++ni)
                    acc[mi][ni] = __builtin_amdgcn_mfma_f32_16x16x32_f16(
                        af[mi], bf[ni], acc[mi][ni], 0, 0, 0);
        }
        {
            f16x8 af[4], bf[4];
            #pragma unroll
            for (int mi = 0; mi < 4; ++mi)
                af[mi] = *(const f16x8*)&As1[(wm * 64 + mi * 16 + mfm) * 32 + quad * 8];
            #pragma unroll
            for (int ni = 0; ni < 4; ++ni)
                bf[ni] = *(const f16x8*)&Bs1[(wn * 64 + ni * 16 + mfm) * 32 + quad * 8];
            #pragma unroll
            for (int mi = 0; mi < 4; ++mi)
                #pragma unroll
                for (int ni = 0; ni < 4; ++ni)
                    acc[mi][ni] = __builtin_amdgcn_mfma_f32_16x16x32_f16(
                        af[mi], bf[ni], acc[mi][ni], 0, 0, 0);
        }
        __syncthreads();
    }

    const int orow = row0 + wm * 64;
    const int ocol = col0 + wn * 64;
    #pragma unroll
    for (int mi = 0; mi < 4; ++mi) {
        #pragma unroll
        for (int r = 0; r < 4; ++r) {
            int row = orow + mi * 16 + quad * 4 + r;
            #pragma unroll
            for (int ni = 0; ni < 4; ++ni)
                outp[(size_t)row * L_ + ocol + ni * 16 + mfm] = (f16)acc[mi][ni][r];
        }
    }
}

// ---------------- conv_transpose overlap-add gather on OPT[e][p] layout ----------------
__global__ __launch_bounds__(256) void gather_kernel(const f16* __restrict__ OPT,
                                                     const float* __restrict__ rowsum,
                                                     float* __restrict__ out_b) {
    int idx = blockIdx.x * 256 + threadIdx.x;
    if (idx >= C_ * H_ * W_) return;
    int X = idx & 127, Y = (idx >> 7) & 127, c = idx >> 14;
    int kyp = (Y + 1) & 1;
    int kxp = (X + 1) & 1;
    float sum = 0.f;
    #pragma unroll
    for (int ky = kyp; ky < 4; ky += 2) {
        int py = (Y + 1 - ky) >> 1;
        if ((unsigned)py >= 64u) continue;
        #pragma unroll
        for (int kx = kxp; kx < 4; kx += 2) {
            int px = (X + 1 - kx) >> 1;
            if ((unsigned)px >= 64u) continue;
            int p = py * 64 + px;
            int e = c * 16 + ky * 4 + kx;
            sum += (float)OPT[(size_t)e * L_ + p] * __builtin_amdgcn_rcpf(rowsum[p]);
        }
    }
    out_b[idx] = 0.25f * sum;
}

extern "C" void kernel_launch(void* const* d_in, const int* in_sizes, int n_in,
                              void* d_out, int out_size, void* d_ws, size_t ws_size,
                              hipStream_t stream) {
    const float* bg = (const float*)d_in[0];
    const float* fg = (const float*)d_in[1];
    float* out = (float*)d_out;
    char* w8 = (char*)d_ws;

    // workspace (bytes), total ~118 MB (ws_size = 256 MiB per fill counters)
    f16*   Fext       = (f16*)  (w8);                 //  2,293,760  B x 4480 x 64
    float* n2         = (float*)(w8 + 2293760);       //     71,680  B x 4480
    float* nrm_all    = (float*)(w8 + 2365440);       //     65,536  B x 4096
    float* rowsum_all = (float*)(w8 + 2430976);       //     65,536  B x 4096
    int*   flags      = (int*)  (w8 + 2496512);       //      4,096  32 x 32
    f16*   VT_all     = (f16*)  (w8 + 2500608);       // 33,554,432  B x E2 x L
    f16*   Hs         = (f16*)  (w8 + 36055040);      // 40,140,800  4480 x 4480 (per-sample)
    f16*   Eb         = (f16*)  (w8 + 76195840);      // 33,554,432  (per-sample)
    f16*   OPT        = (f16*)  (w8 + 109750272);     //  8,388,608  E2 x L (per-sample)

    hipMemsetAsync(Fext, 0, (size_t)B_ * GP * 64 * sizeof(f16), stream);
    hipMemsetAsync(n2, 0, (size_t)B_ * GP * sizeof(float), stream);
    hipMemsetAsync(rowsum_all, 0, (size_t)B_ * L_ * sizeof(float), stream);

    fbuild_kernel<<<dim3(64, B_), 256, 0, stream>>>(fg, Fext, n2);
    norm_kernel<<<dim3(32, B_), 128, 0, stream>>>(n2, nrm_all);
    v_kernel<<<dim3((L_ * E2) / 256, B_), 256, 0, stream>>>(bg, VT_all);

    for (int b = 0; b < B_; ++b) {
        const f16* F_b     = Fext + (size_t)b * GP * 64;
        const float* nrm_b = nrm_all + (size_t)b * L_;
        float* rowsum_b    = rowsum_all + (size_t)b * L_;
        const f16* VT_b    = VT_all + (size_t)b * E2 * L_;
        float* out_b       = out + (size_t)b * C_ * H_ * W_;

        g_gemm<<<dim3(HT, HT), 256, 0, stream>>>(F_b, Hs);
        assemble_kernel<<<dim3(32, 32), 256, 0, stream>>>(
            Hs, nrm_b, Eb, rowsum_b, flags);
        pv_gemm<<<256, 256, 0, stream>>>(VT_b, Eb, OPT, flags);
        gather_kernel<<<(C_ * H_ * W_) / 256, 256, 0, stream>>>(OPT, rowsum_b, out_b);
    }
}

// Round 10
// 384.630 us; speedup vs baseline: 1.8845x; 1.0470x over previous
//
#include <hip/hip_runtime.h>
#include <hip/hip_bf16.h>
#include <math.h>

#define B_  4
#define C_  64
#define H_  128
#define W_  128
#define L_  4096
#define E2  1024
// extended pixel grid 66x66 (zero border = zero-pad semantics), padded
#define GE  66
#define GR  4356        // 66*66 valid rows
#define GP  4480        // padded row/col stride
#define HT  35          // H tile grid (stride-126 overlapping 128-tiles)
#define GSTR 130        // LDS G-tile stride (pad vs 128)
#define SCR_THR (-17.45f)   // screen threshold (exact cutoff -17.5, margin 0.05)

typedef _Float16 f16;
typedef f16 f16x2 __attribute__((ext_vector_type(2)));
typedef f16 f16x8 __attribute__((ext_vector_type(8)));
typedef float f32x4 __attribute__((ext_vector_type(4)));

__device__ __forceinline__ void gload16(const void* g, void* l) {
    __builtin_amdgcn_global_load_lds(
        (const __attribute__((address_space(1))) unsigned int*)g,
        (__attribute__((address_space(3))) unsigned int*)l, 16, 0, 0);
}

// ---------------- fused bilinear resize (128->64 align_corners) + transpose to
// Fext[b][r][c] f16 (r = (y+1)*66 + x+1; borders/tail pre-zeroed) + n2[r] ----------------
__global__ __launch_bounds__(256) void fbuild_kernel(const float* __restrict__ fg,
                                                     f16* __restrict__ Fext,
                                                     float* __restrict__ n2) {
    int y = blockIdx.x, b = blockIdx.y;
    int tid = threadIdx.x;
    __shared__ float T[64][65];
    const float sc = 127.0f / 63.0f;
    float yf = y * sc;
    int y0 = (int)floorf(yf); if (y0 > 127) y0 = 127;
    int y1 = min(y0 + 1, 127);
    float wy = yf - (float)y0;
    {
        int x = tid & 63;
        float xf = x * sc;
        int x0 = (int)floorf(xf); if (x0 > 127) x0 = 127;
        int x1 = min(x0 + 1, 127);
        float wx = xf - (float)x0;
        for (int cp = 0; cp < 16; ++cp) {
            int c = cp * 4 + (tid >> 6);
            const float* p = fg + (size_t)(b * 64 + c) * (128 * 128);
            float a = p[y0 * 128 + x0], bb = p[y0 * 128 + x1];
            float cc = p[y1 * 128 + x0], dd = p[y1 * 128 + x1];
            float t0 = a * (1.f - wy) + cc * wy;
            float t1 = bb * (1.f - wy) + dd * wy;
            T[c][x] = t0 * (1.f - wx) + t1 * wx;
        }
    }
    __syncthreads();
    int c = tid & 63, xi = tid >> 6;
    for (int j = 0; j < 16; ++j) {
        int x = xi + 4 * j;
        float v = T[c][x];
        int r = (y + 1) * GE + 1 + x;
        Fext[((size_t)b * GP + r) * 64 + c] = (f16)v;
        float s = v * v;
        #pragma unroll
        for (int off = 32; off; off >>= 1) s += __shfl_xor(s, off);
        if (c == 0) n2[b * GP + r] = s;
    }
}

// ---------------- nrm[p] = clamp(sqrt(3x3 boxsum of n2), 1e-4) + per-128-block min/max ----------------
__global__ __launch_bounds__(128) void norm_kernel(const float* __restrict__ n2,
                                                   float* __restrict__ nrm_all,
                                                   float* __restrict__ minN_all,
                                                   float* __restrict__ maxN_all) {
    __shared__ float smn[2], smx[2];
    int t = threadIdx.x, pb = blockIdx.x, b = blockIdx.y;
    int p = pb * 128 + t;
    int pe = ((p >> 6) + 1) * GE + (p & 63) + 1;
    const float* n2b = n2 + (size_t)b * GP;
    float s = 0.f;
    #pragma unroll
    for (int dy = -1; dy <= 1; ++dy)
        #pragma unroll
        for (int dx = -1; dx <= 1; ++dx) s += n2b[pe + dy * GE + dx];
    float nv = fmaxf(sqrtf(s), 1e-4f);
    nrm_all[b * L_ + p] = nv;
    float mn = nv, mx = nv;
    #pragma unroll
    for (int off = 32; off; off >>= 1) {
        mn = fminf(mn, __shfl_xor(mn, off));
        mx = fmaxf(mx, __shfl_xor(mx, off));
    }
    if ((t & 63) == 0) { smn[t >> 6] = mn; smx[t >> 6] = mx; }
    __syncthreads();
    if (t == 0) {
        minN_all[b * 32 + pb] = fminf(smn[0], smn[1]);
        maxN_all[b * 32 + pb] = fmaxf(smx[0], smx[1]);
    }
}

// ---------------- v2: VT[b][e][l] via LDS-staged bg channel (coalesced both ways) ----------------
__global__ __launch_bounds__(256) void v2_kernel(const float* __restrict__ bg,
                                                 f16* __restrict__ VT_all) {
    int c = blockIdx.x, b = blockIdx.y;
    int tid = threadIdx.x;
    __shared__ f16 T[128 * GSTR];
    const float* src = bg + ((size_t)b * 64 + c) * (128 * 128);
    for (int i = tid; i < 128 * 128; i += 256) {
        int r = i >> 7, x = i & 127;
        T[r * GSTR + x] = (f16)src[i];
    }
    __syncthreads();
    #pragma unroll
    for (int r = 0; r < 16; ++r) {
        int ky = r >> 2, kx = r & 3;
        f16* dst = VT_all + (((size_t)b * E2) + c * 16 + r) * L_;
        for (int it = 0; it < 8; ++it) {
            int t2 = it * 256 + tid;        // pair index 0..2047
            int l = 2 * t2;
            int ly = l >> 6, lx = l & 63;
            int by = 2 * ly - 1 + ky;
            int bx0 = 2 * lx - 1 + kx;
            f16 v0 = (f16)0.f, v1 = (f16)0.f;
            if ((unsigned)by < 128u) {
                if ((unsigned)bx0 < 128u) v0 = T[by * GSTR + bx0];
                int bx1 = bx0 + 2;
                if ((unsigned)bx1 < 128u) v1 = T[by * GSTR + bx1];
            }
            f16x2 w; w.x = v0; w.y = v1;
            *(f16x2*)&dst[l] = w;
        }
    }
}

// ---------------- pixel Gram GEMM + fused dx-diag-sum epilogue (round-9 verified) ----------------
__global__ __launch_bounds__(256) void g_gemm(const f16* __restrict__ F,
                                              f16* __restrict__ Hs) {
    __shared__ __align__(16) f16 pool[128 * GSTR];   // staging aliases Gs
    f16* As0 = pool;
    f16* As1 = pool + 4096;
    f16* Bs0 = pool + 8192;
    f16* Bs1 = pool + 12288;
    f16* Gs  = pool;
    const int bx = blockIdx.x, by = blockIdx.y;
    const int tid = threadIdx.x;
    const int w = tid >> 6, lane = tid & 63;
    const int row0 = by * 126, col0 = bx * 126;

    const int srow = w * 32 + (lane >> 2);
    const int scol = (lane & 3) * 8;
    const f16* gA = F + (size_t)(row0 + srow) * 64 + scol;
    const f16* gB = F + (size_t)(col0 + srow) * 64 + scol;
    const int l0 = (w * 32) * 32, l1 = (w * 32 + 16) * 32;

    gload16(gA,                As0 + l0);
    gload16(gA + 16 * 64,      As0 + l1);
    gload16(gA + 32,           As1 + l0);
    gload16(gA + 32 + 16 * 64, As1 + l1);
    gload16(gB,                Bs0 + l0);
    gload16(gB + 16 * 64,      Bs0 + l1);
    gload16(gB + 32,           Bs1 + l0);
    gload16(gB + 32 + 16 * 64, Bs1 + l1);

    const int wm = w >> 1, wn = w & 1;
    const int mfm = lane & 15, quad = lane >> 4;
    f32x4 acc[4][4] = {};
    __syncthreads();
    {
        f16x8 af[4], bf[4];
        #pragma unroll
        for (int mi = 0; mi < 4; ++mi)
            af[mi] = *(const f16x8*)&As0[(wm * 64 + mi * 16 + mfm) * 32 + quad * 8];
        #pragma unroll
        for (int ni = 0; ni < 4; ++ni)
            bf[ni] = *(const f16x8*)&Bs0[(wn * 64 + ni * 16 + mfm) * 32 + quad * 8];
        #pragma unroll
        for (int mi = 0; mi < 4; ++mi)
            #pragma unroll
            for (int ni = 0; ni < 4; ++ni)
                acc[mi][ni] = __builtin_amdgcn_mfma_f32_16x16x32_f16(
                    af[mi], bf[ni], acc[mi][ni], 0, 0, 0);
    }
    {
        f16x8 af[4], bf[4];
        #pragma unroll
        for (int mi = 0; mi < 4; ++mi)
            af[mi] = *(const f16x8*)&As1[(wm * 64 + mi * 16 + mfm) * 32 + quad * 8];
        #pragma unroll
        for (int ni = 0; ni < 4; ++ni)
            bf[ni] = *(const f16x8*)&Bs1[(wn * 64 + ni * 16 + mfm) * 32 + quad * 8];
        #pragma unroll
        for (int mi = 0; mi < 4; ++mi)
            #pragma unroll
            for (int ni = 0; ni < 4; ++ni)
                acc[mi][ni] = __builtin_amdgcn_mfma_f32_16x16x32_f16(
                    af[mi], bf[ni], acc[mi][ni], 0, 0, 0);
    }
    __syncthreads();   // staging LDS dead; safe to overwrite with Gs
    #pragma unroll
    for (int mi = 0; mi < 4; ++mi)
        #pragma unroll
        for (int r = 0; r < 4; ++r) {
            int rl = wm * 64 + mi * 16 + quad * 4 + r;
            #pragma unroll
            for (int ni = 0; ni < 4; ++ni)
                Gs[rl * GSTR + wn * 64 + ni * 16 + mfm] = (f16)acc[mi][ni][r];
        }
    __syncthreads();
    if (lane < 63) {
        int c1 = 2 * lane + 1;
        for (int j = 0; j < 32; ++j) {
            int r = 1 + w + 4 * j;
            if (r > 126) break;
            float h1 = (float)Gs[(r - 1) * GSTR + c1 - 1] + (float)Gs[r * GSTR + c1]
                     + (float)Gs[(r + 1) * GSTR + c1 + 1];
            float h2 = (float)Gs[(r - 1) * GSTR + c1] + (float)Gs[r * GSTR + c1 + 1]
                     + (float)Gs[(r + 1) * GSTR + c1 + 2];
            f16x2 hv; hv.x = (f16)h1; hv.y = (f16)h2;
            *(f16x2*)&Hs[(size_t)(row0 + r) * GP + col0 + 2 * lane] = hv;
        }
    }
}

// ---------------- Hmax[r][Y] = max over cols [66Y, 66Y+64) of Hs row r ----------------
// (exactly the column range assemble reads for segment Y; rows 0..4355)
__global__ __launch_bounds__(256) void hmax_kernel(const f16* __restrict__ Hs,
                                                   float* __restrict__ Hmax) {
    int t = blockIdx.x * 256 + threadIdx.x;
    if (t >= GR * GE) return;
    int r = t / GE, Y = t - r * GE;
    const f16* p = Hs + (size_t)r * GP + 66 * Y;
    float m = -1e30f;
    #pragma unroll
    for (int i = 0; i < 32; ++i) {
        f16x2 v = *(const f16x2*)&p[2 * i];
        m = fmaxf(m, fmaxf((float)v.x, (float)v.y));
    }
    Hmax[t] = m;
}

// ---------------- S assembly v4: sound Hmax screen, then exact (round-9 body) ----------------
// Screen: S_max(p) <= sum_dy max(Hmax[pe+66dy][Y1], Hmax[pe+66dy][Y1+1]);
// logit bound uses min/max block norm of the l-block. Bound >= exact max computed
// from the same f16 H values -> skipping below SCR_THR is sound vs the -17.5 cutoff.
__global__ __launch_bounds__(256) void assemble_kernel(const f16* __restrict__ Hs,
                                                       const float* __restrict__ Hmax,
                                                       const float* __restrict__ nrm_b,
                                                       const float* __restrict__ minN_b,
                                                       const float* __restrict__ maxN_b,
                                                       f16* __restrict__ Eb,
                                                       float* __restrict__ rowsum_b,
                                                       int* __restrict__ flags) {
    const int lblk = blockIdx.x, pblk = blockIdx.y;
    const int tid = threadIdx.x, wv = tid >> 6, lane = tid & 63;
    __shared__ float sbp[2];
    __shared__ int skip;
    // ---- screen ----
    {
        float bp = -1e30f;
        if (tid < 128) {
            int p = pblk * 128 + tid;
            int pe = 66 * ((p >> 6) + 1) + (p & 63) + 1;
            float s = 0.f;
            #pragma unroll
            for (int dy = -1; dy <= 1; ++dy) {
                const float* hm = Hmax + (size_t)(pe + dy * 66) * GE + (2 * lblk + 1 + dy);
                s += fmaxf(hm[0], hm[1]);
            }
            float num = (s > 0.f) ? s * (10.0f / minN_b[lblk]) : s * (10.0f / maxN_b[lblk]);
            bp = num - 10.0f * nrm_b[p];
        }
        #pragma unroll
        for (int off = 32; off; off >>= 1) bp = fmaxf(bp, __shfl_xor(bp, off));
        if (tid < 128 && (tid & 63) == 0) sbp[tid >> 6] = bp;
        __syncthreads();
        if (tid == 0) skip = (fmaxf(sbp[0], sbp[1]) < SCR_THR);
        __syncthreads();
        if (skip) {
            if (tid == 0) flags[pblk * 32 + lblk] = 0;
            return;
        }
    }
    // ---- exact (round-9 verified body) ----
    __shared__ f16 Ss[128 * 128];
    __shared__ float nlv[128], npv[128], sred[4];
    if (tid < 128) nlv[tid] = 10.0f / nrm_b[lblk * 128 + tid];
    else           npv[tid - 128] = 10.0f * nrm_b[pblk * 128 + tid - 128];
    __syncthreads();

    const int ly_loc = lane >> 5;
    const int lx = 2 * (lane & 31);
    const int l_local = ly_loc * 64 + lx;
    const int gly = lblk * 2 + ly_loc;
    const float inl0 = nlv[l_local], inl1 = nlv[l_local + 1];

    float mx = -1e30f;
    for (int k = 0; k < 32; ++k) {
        int ip = wv + 4 * k;
        int p = pblk * 128 + ip;
        int pe = 66 * ((p >> 6) + 1) + (p & 63) + 1;
        float s0 = 0.f, s1 = 0.f;
        #pragma unroll
        for (int dy = -1; dy <= 1; ++dy) {
            f16x2 v = *(const f16x2*)&Hs[(size_t)(pe + dy * 66) * GP + 66 * (gly + 1 + dy) + lx];
            s0 += (float)v.x; s1 += (float)v.y;
        }
        float rp = npv[ip];
        float lg0 = s0 * inl0 - rp;
        float lg1 = s1 * inl1 - rp;
        mx = fmaxf(mx, fmaxf(lg0, lg1));
        f16x2 ev; ev.x = (f16)__expf(lg0); ev.y = (f16)__expf(lg1);
        *(f16x2*)&Ss[ip * 128 + l_local] = ev;
    }
    #pragma unroll
    for (int off = 32; off; off >>= 1) mx = fmaxf(mx, __shfl_xor(mx, off));
    if (lane == 0) sred[wv] = mx;
    __syncthreads();
    float bmax = fmaxf(fmaxf(sred[0], sred[1]), fmaxf(sred[2], sred[3]));
    int nz = bmax > -17.5f;
    if (tid == 0) flags[pblk * 32 + lblk] = nz;
    if (!nz) return;

    for (int k = 0; k < 32; ++k) {
        int ip = wv + 4 * k;
        int p = pblk * 128 + ip;
        f16x2 ev = *(const f16x2*)&Ss[ip * 128 + l_local];
        *(f16x2*)&Eb[(size_t)p * L_ + lblk * 128 + l_local] = ev;
        float v = (float)ev.x + (float)ev.y;
        #pragma unroll
        for (int off = 32; off; off >>= 1) v += __shfl_xor(v, off);
        if (lane == 0) atomicAdd(&rowsum_b[p], v);
    }
}

// ---------------- PV MFMA GEMM, batched over samples (1024 blocks = 4/CU) ----------------
__global__ __launch_bounds__(256)
void pv_gemm(const f16* __restrict__ VT_all, const f16* __restrict__ Eb_all,
             f16* __restrict__ OPT_all, const int* __restrict__ flags_all) {
    __shared__ __align__(16) f16 As0[128 * 32];
    __shared__ __align__(16) f16 As1[128 * 32];
    __shared__ __align__(16) f16 Bs0[128 * 32];
    __shared__ __align__(16) f16 Bs1[128 * 32];
    const int lin = blockIdx.x;
    const int b = lin >> 8;
    const int rr = lin & 255;
    const int by = rr & 7;           // e block
    const int bx = rr >> 3;          // p block

    const f16* A  = VT_all + (size_t)b * E2 * L_;
    const f16* Bt = Eb_all + (size_t)b * L_ * L_;
    const int* flags = flags_all + b * 1024;
    f16* outp = OPT_all + (size_t)b * E2 * L_;

    const int tid = threadIdx.x;
    const int w = tid >> 6, lane = tid & 63;
    const int row0 = by * 128, col0 = bx * 128;

    const int srow = w * 32 + (lane >> 2);
    const int scol = (lane & 3) * 8;
    const f16* gA = A + (size_t)(row0 + srow) * L_ + scol;
    const f16* gB = Bt + (size_t)(col0 + srow) * L_ + scol;
    const int l0 = (w * 32) * 32, l1 = (w * 32 + 16) * 32;

    const int wm = w >> 1, wn = w & 1;
    const int mfm = lane & 15, quad = lane >> 4;
    f32x4 acc[4][4] = {};

    for (int k0 = 0; k0 < L_; k0 += 64) {
        if (!flags[bx * 32 + (k0 >> 7)]) continue;
        gload16(gA + k0,                        As0 + l0);
        gload16(gA + k0 + (size_t)16 * L_,      As0 + l1);
        gload16(gA + k0 + 32,                   As1 + l0);
        gload16(gA + k0 + 32 + (size_t)16 * L_, As1 + l1);
        gload16(gB + k0,                        Bs0 + l0);
        gload16(gB + k0 + (size_t)16 * L_,      Bs0 + l1);
        gload16(gB + k0 + 32,                   Bs1 + l0);
        gload16(gB + k0 + 32 + (size_t)16 * L_, Bs1 + l1);
        __syncthreads();
        {
            f16x8 af[4], bf[4];
            #pragma unroll
            for (int mi = 0; mi < 4; ++mi)
                af[mi] = *(const f16x8*)&As0[(wm * 64 + mi * 16 + mfm) * 32 + quad * 8];
            #pragma unroll
            for (int ni = 0; ni < 4; ++ni)
                bf[ni] = *(const f16x8*)&Bs0[(wn * 64 + ni * 16 + mfm) * 32 + quad * 8];
            #pragma unroll
            for (int mi = 0; mi < 4; ++mi)
                #pragma unroll
                for (int ni = 0; ni < 4; ++ni)
                    acc[mi][ni] = __builtin_amdgcn_mfma_f32_16x16x32_f16(
                        af[mi], bf[ni], acc[mi][ni], 0, 0, 0);
        }
        {
            f16x8 af[4], bf[4];
            #pragma unroll
            for (int mi = 0; mi < 4; ++mi)
                af[mi] = *(const f16x8*)&As1[(wm * 64 + mi * 16 + mfm) * 32 + quad * 8];
            #pragma unroll
            for (int ni = 0; ni < 4; ++ni)
                bf[ni] = *(const f16x8*)&Bs1[(wn * 64 + ni * 16 + mfm) * 32 + quad * 8];
            #pragma unroll
            for (int mi = 0; mi < 4; ++mi)
                #pragma unroll
                for (int ni = 0; ni < 4; ++ni)
                    acc[mi][ni] = __builtin_amdgcn_mfma_f32_16x16x32_f16(
                        af[mi], bf[ni], acc[mi][ni], 0, 0, 0);
        }
        __syncthreads();
    }

    const int orow = row0 + wm * 64;
    const int ocol = col0 + wn * 64;
    #pragma unroll
    for (int mi = 0; mi < 4; ++mi) {
        #pragma unroll
        for (int r = 0; r < 4; ++r) {
            int row = orow + mi * 16 + quad * 4 + r;
            #pragma unroll
            for (int ni = 0; ni < 4; ++ni)
                outp[(size_t)row * L_ + ocol + ni * 16 + mfm] = (f16)acc[mi][ni][r];
        }
    }
}

// ---------------- conv_transpose overlap-add gather, batched over samples ----------------
__global__ __launch_bounds__(256) void gather_kernel(const f16* __restrict__ OPT_all,
                                                     const float* __restrict__ rowsum_all,
                                                     float* __restrict__ out) {
    int b = blockIdx.y;
    const f16* OPT = OPT_all + (size_t)b * E2 * L_;
    const float* rowsum = rowsum_all + (size_t)b * L_;
    float* out_b = out + (size_t)b * C_ * H_ * W_;
    int idx = blockIdx.x * 256 + threadIdx.x;
    if (idx >= C_ * H_ * W_) return;
    int X = idx & 127, Y = (idx >> 7) & 127, c = idx >> 14;
    int kyp = (Y + 1) & 1;
    int kxp = (X + 1) & 1;
    float sum = 0.f;
    #pragma unroll
    for (int ky = kyp; ky < 4; ky += 2) {
        int py = (Y + 1 - ky) >> 1;
        if ((unsigned)py >= 64u) continue;
        #pragma unroll
        for (int kx = kxp; kx < 4; kx += 2) {
            int px = (X + 1 - kx) >> 1;
            if ((unsigned)px >= 64u) continue;
            int p = py * 64 + px;
            int e = c * 16 + ky * 4 + kx;
            sum += (float)OPT[(size_t)e * L_ + p] * __builtin_amdgcn_rcpf(rowsum[p]);
        }
    }
    out_b[idx] = 0.25f * sum;
}

extern "C" void kernel_launch(void* const* d_in, const int* in_sizes, int n_in,
                              void* d_out, int out_size, void* d_ws, size_t ws_size,
                              hipStream_t stream) {
    const float* bg = (const float*)d_in[0];
    const float* fg = (const float*)d_in[1];
    float* out = (float*)d_out;
    char* w8 = (char*)d_ws;

    // workspace (bytes), total ~245 MB (ws_size = 256 MiB per fill counters)
    f16*   Fext       = (f16*)  (w8);                 //   2,293,760  B x 4480 x 64
    float* n2         = (float*)(w8 + 2293760);       //      71,680  B x 4480
    float* nrm_all    = (float*)(w8 + 2365440);       //      65,536  B x 4096
    float* minN_all   = (float*)(w8 + 2430976);       //         512  B x 32
    float* maxN_all   = (float*)(w8 + 2431488);       //         512  B x 32
    float* rowsum_all = (float*)(w8 + 2432000);       //      65,536  B x 4096
    int*   flags_all  = (int*)  (w8 + 2497536);       //      16,384  B x 32 x 32
    float* Hmax       = (float*)(w8 + 2513920);       //   1,149,984  4356 x 66 (per-sample)
    f16*   VT_all     = (f16*)  (w8 + 3664128);       //  33,554,432  B x E2 x L
    f16*   OPT_all    = (f16*)  (w8 + 37218560);      //  33,554,432  B x E2 x L
    f16*   Hs         = (f16*)  (w8 + 70772992);      //  40,140,800  4480 x 4480 (per-sample)
    f16*   Eb_all     = (f16*)  (w8 + 110913792);     // 134,217,728  B x L x L

    hipMemsetAsync(Fext, 0, (size_t)B_ * GP * 64 * sizeof(f16), stream);
    hipMemsetAsync(n2, 0, (size_t)B_ * GP * sizeof(float), stream);
    hipMemsetAsync(rowsum_all, 0, (size_t)B_ * L_ * sizeof(float), stream);

    fbuild_kernel<<<dim3(64, B_), 256, 0, stream>>>(fg, Fext, n2);
    norm_kernel<<<dim3(32, B_), 128, 0, stream>>>(n2, nrm_all, minN_all, maxN_all);
    v2_kernel<<<dim3(64, B_), 256, 0, stream>>>(bg, VT_all);

    for (int b = 0; b < B_; ++b) {
        const f16* F_b     = Fext + (size_t)b * GP * 64;
        const float* nrm_b = nrm_all + (size_t)b * L_;
        float* rowsum_b    = rowsum_all + (size_t)b * L_;
        f16* Eb_b          = Eb_all + (size_t)b * L_ * L_;
        int* flags_b       = flags_all + b * 1024;

        g_gemm<<<dim3(HT, HT), 256, 0, stream>>>(F_b, Hs);
        hmax_kernel<<<(GR * GE + 255) / 256, 256, 0, stream>>>(Hs, Hmax);
        assemble_kernel<<<dim3(32, 32), 256, 0, stream>>>(
            Hs, Hmax, nrm_b, minN_all + b * 32, maxN_all + b * 32,
            Eb_b, rowsum_b, flags_b);
    }

    pv_gemm<<<1024, 256, 0, stream>>>(VT_all, Eb_all, OPT_all, flags_all);
    gather_kernel<<<dim3((C_ * H_ * W_) / 256, B_), 256, 0, stream>>>(
        OPT_all, rowsum_all, out);
}